// Round 8
// baseline (205.820 us; speedup 1.0000x reference)
//
#include <hip/hip_runtime.h>

#define NROWS 8192
#define NCENT 4096
#define DIM   256

typedef short bf16x8 __attribute__((ext_vector_type(8)));
typedef float f32x4  __attribute__((ext_vector_type(4)));

// fp32 -> bf16 round-to-nearest-even
__device__ inline unsigned short f2bf(float f) {
    unsigned u = __float_as_uint(f);
    return (unsigned short)((u + 0x7fffu + ((u >> 16) & 1u)) >> 16);
}

// ---------------------------------------------------------------------------
// Norms: one wave per row. ws[0..8191]=||x||^2, ws[8192..12287]=||c||^2
// ---------------------------------------------------------------------------
__global__ __launch_bounds__(256) void norms_kernel(const float* __restrict__ x,
                                                    const float* __restrict__ c,
                                                    float* __restrict__ ws) {
    int t = threadIdx.x, lane = t & 63;
    int gw = blockIdx.x * 4 + (t >> 6);   // 0..12287
    const float* src;
    float* dst;
    if (gw < NROWS) { src = x + (size_t)gw * DIM;           dst = ws + gw; }
    else            { src = c + (size_t)(gw - NROWS) * DIM; dst = ws + gw; }
    float4 v = ((const float4*)src)[lane];
    float s = v.x * v.x + v.y * v.y + v.z * v.z + v.w * v.w;
    #pragma unroll
    for (int m = 32; m; m >>= 1) s += __shfl_xor(s, m);
    if (lane == 0) *dst = s;
}

// ---------------------------------------------------------------------------
// Pack: fp32 row-major -> bf16 MFMA-fragment-packed blocks (as R7).
// Block (tg,ks) at (tg*8+ks)*1024B; lane (g,lr) bytes lane*16..+15 hold
// rows tg*16+lr, k=ks*32+g*8..+7 — the 16x16x32 fragment for that lane.
// ---------------------------------------------------------------------------
__global__ __launch_bounds__(256) void pack_kernel(const float* __restrict__ x,
                                                   const float* __restrict__ c,
                                                   unsigned short* __restrict__ xp,
                                                   unsigned short* __restrict__ cp) {
    const int t = threadIdx.x, lane = t & 63;
    const int task = blockIdx.x * 4 + (t >> 6);     // 0..6143
    const int lr = lane & 15, g = lane >> 4;
    const float* src;
    unsigned short* dst;
    int tg, ks;
    if (task < (NROWS / 16) * 8) {                  // x: 512 groups * 8 ksteps
        tg = task >> 3; ks = task & 7;
        src = x;  dst = xp + (size_t)task * 512;
    } else {
        int tk = task - (NROWS / 16) * 8;           // c: 256 groups * 8 ksteps
        tg = tk >> 3; ks = tk & 7;
        src = c;  dst = cp + (size_t)tk * 512;
    }
    const float* p = src + (size_t)(tg * 16 + lr) * DIM + ks * 32 + g * 8;
    float4 f0 = *(const float4*)p;
    float4 f1 = *(const float4*)(p + 4);
    union { unsigned short s[8]; int4 v; } u;
    u.s[0] = f2bf(f0.x); u.s[1] = f2bf(f0.y); u.s[2] = f2bf(f0.z); u.s[3] = f2bf(f0.w);
    u.s[4] = f2bf(f1.x); u.s[5] = f2bf(f1.y); u.s[6] = f2bf(f1.z); u.s[7] = f2bf(f1.w);
    *(int4*)(dst + lane * 8) = u.v;
}

// ---------------------------------------------------------------------------
// Main kernel (R8): A-RESIDENT / B-STREAM. One wave per block.
// Wave holds its whole A tile (64 rows x 256 k = 32 frags = 128 VGPRs) and
// streams B contiguously through 16 n-chunks of 16 cols: per chunk
// 8 coalesced 1KB loads -> 32 MFMAs -> inline fused epilogue
// (t = kx2 + kc2 + 2*sigma*dot; clamp; __expf; fma into per-lane sums).
// Two B register sets alternate by parity (NO register copies — R7's
// rotation movs were ~20% VALU). No LDS, no barriers; depth-2 prefetch.
// XCD swizzle: each XCD owns 16 m-tiles x all cols: A 512KB + B 2MB < 4MB L2.
// ---------------------------------------------------------------------------
__global__ __launch_bounds__(64, 2) void rbf_stream(const unsigned short* __restrict__ xp,
                                                    const unsigned short* __restrict__ cp,
                                                    const float* __restrict__ w,
                                                    const float* __restrict__ sigp,
                                                    const float* __restrict__ norms,
                                                    float* __restrict__ out) {
    const int lane = threadIdx.x;           // one wave per block
    const int lr = lane & 15, g = lane >> 4;

    const int lin = blockIdx.x;             // 0..2047
    const int xcd = lin & 7;
    const int pos = lin >> 3;               // 0..255
    const int m0  = (xcd * 16 + (pos >> 4)) * 64;   // 64-row tile
    const int n0  = (pos & 15) * 256;               // 256-col split

    // ---- A resident: 4 m-frags x 8 k-steps (32KB contiguous, coalesced) ----
    bf16x8 A[4][8];
    {
        const unsigned short* ap = xp + ((size_t)(m0 >> 4) * 8) * 512 + lane * 8;
        #pragma unroll
        for (int i = 0; i < 4; ++i)
            #pragma unroll
            for (int s = 0; s < 8; ++s)
                A[i][s] = *(const bf16x8*)(ap + (size_t)(i * 8 + s) * 512);
    }

    // ---- fused-exp constants: phi = exp(min(t,0)), t = -sigma*d2 ----
    const float K = -sigp[0];               // t = K*x2 + K*c2 + (2*sigma)*dot
    const float M = -2.0f * K;
    float kx2[4][4];
    #pragma unroll
    for (int i = 0; i < 4; ++i) {
        float4 v = *(const float4*)(norms + m0 + 16 * i + 4 * g);
        kx2[i][0] = K * v.x; kx2[i][1] = K * v.y;
        kx2[i][2] = K * v.z; kx2[i][3] = K * v.w;
    }

    float sums[4][4];
    #pragma unroll
    for (int i = 0; i < 4; ++i)
        #pragma unroll
        for (int r = 0; r < 4; ++r) sums[i][r] = 0.f;

    // ---- B stream: 16 chunks x 8KB, fully contiguous in cp ----
    const unsigned short* bp = cp + ((size_t)(n0 >> 4) * 8) * 512 + lane * 8;

    bf16x8 B0[8], B1[8];
    #pragma unroll
    for (int s = 0; s < 8; ++s) B0[s] = *(const bf16x8*)(bp + s * 512);
    #pragma unroll
    for (int s = 0; s < 8; ++s) B1[s] = *(const bf16x8*)(bp + 4096 + s * 512);

    #pragma unroll
    for (int c = 0; c < 16; c += 2) {
        // ================= chunk c (B0) =================
        {
            f32x4 acc[4] = {f32x4{0,0,0,0}, f32x4{0,0,0,0}, f32x4{0,0,0,0}, f32x4{0,0,0,0}};
            #pragma unroll
            for (int s = 0; s < 8; ++s)
                #pragma unroll
                for (int i = 0; i < 4; ++i)
                    acc[i] = __builtin_amdgcn_mfma_f32_16x16x32_bf16(A[i][s], B0[s], acc[i], 0, 0, 0);
            if (c + 2 < 16) {   // prefetch chunk c+2 into B0 (regs just consumed)
                #pragma unroll
                for (int s = 0; s < 8; ++s)
                    B0[s] = *(const bf16x8*)(bp + (size_t)(c + 2) * 4096 + s * 512);
            }
            const int col = n0 + 16 * c + lr;
            const float kc2 = K * norms[NROWS + col];
            const float wv  = w[col];
            #pragma unroll
            for (int i = 0; i < 4; ++i)
                #pragma unroll
                for (int r = 0; r < 4; ++r) {
                    float t = fmaf(M, acc[i][r], kx2[i][r] + kc2);
                    t = fminf(t, 0.0f);                      // d2 clamp
                    sums[i][r] = fmaf(wv, __expf(t), sums[i][r]);
                }
        }
        // ================= chunk c+1 (B1) =================
        {
            f32x4 acc[4] = {f32x4{0,0,0,0}, f32x4{0,0,0,0}, f32x4{0,0,0,0}, f32x4{0,0,0,0}};
            #pragma unroll
            for (int s = 0; s < 8; ++s)
                #pragma unroll
                for (int i = 0; i < 4; ++i)
                    acc[i] = __builtin_amdgcn_mfma_f32_16x16x32_bf16(A[i][s], B1[s], acc[i], 0, 0, 0);
            if (c + 3 < 16) {   // prefetch chunk c+3 into B1
                #pragma unroll
                for (int s = 0; s < 8; ++s)
                    B1[s] = *(const bf16x8*)(bp + (size_t)(c + 3) * 4096 + s * 512);
            }
            const int col = n0 + 16 * (c + 1) + lr;
            const float kc2 = K * norms[NROWS + col];
            const float wv  = w[col];
            #pragma unroll
            for (int i = 0; i < 4; ++i)
                #pragma unroll
                for (int r = 0; r < 4; ++r) {
                    float t = fmaf(M, acc[i][r], kx2[i][r] + kc2);
                    t = fminf(t, 0.0f);
                    sums[i][r] = fmaf(wv, __expf(t), sums[i][r]);
                }
        }
    }

    // ---- reduce over the 16 lr-lanes; one atomic per row ----
    #pragma unroll
    for (int i = 0; i < 4; ++i)
        #pragma unroll
        for (int r = 0; r < 4; ++r) {
            float v = sums[i][r];
            v += __shfl_xor(v, 1);
            v += __shfl_xor(v, 2);
            v += __shfl_xor(v, 4);
            v += __shfl_xor(v, 8);
            if (lr == 0) atomicAdd(&out[m0 + 16 * i + 4 * g + r], v);
        }
}

// ---------------------------------------------------------------------------
// Fallback (R2 kernel) if ws is too small for the packed scratch copies.
// ---------------------------------------------------------------------------
__global__ __launch_bounds__(256) void rbf_kernel(const float* __restrict__ x,
                                                  const float* __restrict__ cent,
                                                  const float* __restrict__ w,
                                                  const float* __restrict__ sigp,
                                                  const float* __restrict__ norms,
                                                  float* __restrict__ out) {
    __shared__ __align__(16) short xs[64 * 32];
    __shared__ __align__(16) short cs[64 * 32];
    const int t = threadIdx.x;
    const int m0 = blockIdx.y * 64, n0 = blockIdx.x * 64;
    const int srow = t >> 2, seg = t & 3;
    const int pchunk = seg ^ ((srow >> 1) & 3);
    const int sidx = srow * 32 + pchunk * 8;
    const float* xg = x    + (size_t)(m0 + srow) * DIM + seg * 8;
    const float* cg = cent + (size_t)(n0 + srow) * DIM + seg * 8;
    const int lane = t & 63, wave = t >> 6;
    const int lr = lane & 15, lg = lane >> 4;
    const int arow = 16 * wave + lr;
    const int aidx = arow * 32 + ((lg ^ ((arow >> 1) & 3)) * 8);
    f32x4 acc[4] = {f32x4{0,0,0,0}, f32x4{0,0,0,0}, f32x4{0,0,0,0}, f32x4{0,0,0,0}};
    for (int k0 = 0; k0 < DIM; k0 += 32) {
        float4 f0 = *(const float4*)(xg + k0);
        float4 f1 = *(const float4*)(xg + k0 + 4);
        float4 g0 = *(const float4*)(cg + k0);
        float4 g1 = *(const float4*)(cg + k0 + 4);
        __syncthreads();
        union { unsigned short s[8]; int4 v; } ux, uc;
        ux.s[0]=f2bf(f0.x); ux.s[1]=f2bf(f0.y); ux.s[2]=f2bf(f0.z); ux.s[3]=f2bf(f0.w);
        ux.s[4]=f2bf(f1.x); ux.s[5]=f2bf(f1.y); ux.s[6]=f2bf(f1.z); ux.s[7]=f2bf(f1.w);
        uc.s[0]=f2bf(g0.x); uc.s[1]=f2bf(g0.y); uc.s[2]=f2bf(g0.z); uc.s[3]=f2bf(g0.w);
        uc.s[4]=f2bf(g1.x); uc.s[5]=f2bf(g1.y); uc.s[6]=f2bf(g1.z); uc.s[7]=f2bf(g1.w);
        *(int4*)(xs + sidx) = ux.v;
        *(int4*)(cs + sidx) = uc.v;
        __syncthreads();
        bf16x8 a = *(const bf16x8*)(xs + aidx);
        #pragma unroll
        for (int bt = 0; bt < 4; ++bt) {
            const int brow = 16 * bt + lr;
            bf16x8 b = *(const bf16x8*)(cs + brow * 32 + ((lg ^ ((brow >> 1) & 3)) * 8));
            acc[bt] = __builtin_amdgcn_mfma_f32_16x16x32_bf16(a, b, acc[bt], 0, 0, 0);
        }
    }
    const float sigma = sigp[0];
    const int rbase = m0 + 16 * wave + lg * 4;
    float x2v[4];
    #pragma unroll
    for (int r = 0; r < 4; ++r) x2v[r] = norms[rbase + r];
    float rs[4] = {0.f, 0.f, 0.f, 0.f};
    #pragma unroll
    for (int bt = 0; bt < 4; ++bt) {
        const int col = n0 + 16 * bt + lr;
        const float c2v = norms[NROWS + col];
        const float wvv = w[col];
        #pragma unroll
        for (int r = 0; r < 4; ++r) {
            float d2 = x2v[r] + c2v - 2.0f * acc[bt][r];
            d2 = fmaxf(d2, 0.0f);
            rs[r] += wvv * __expf(-sigma * d2);
        }
    }
    #pragma unroll
    for (int r = 0; r < 4; ++r) {
        rs[r] += __shfl_xor(rs[r], 1);
        rs[r] += __shfl_xor(rs[r], 2);
        rs[r] += __shfl_xor(rs[r], 4);
        rs[r] += __shfl_xor(rs[r], 8);
    }
    if (lr == 0) {
        #pragma unroll
        for (int r = 0; r < 4; ++r) atomicAdd(&out[rbase + r], rs[r]);
    }
}

extern "C" void kernel_launch(void* const* d_in, const int* in_sizes, int n_in,
                              void* d_out, int out_size, void* d_ws, size_t ws_size,
                              hipStream_t stream) {
    const float* x    = (const float*)d_in[0];
    const float* cent = (const float*)d_in[1];
    const float* w    = (const float*)d_in[2];
    const float* sig  = (const float*)d_in[3];
    float* out = (float*)d_out;

    const size_t norms_elems = NROWS + NCENT;              // 12288 floats
    const size_t xp_off  = norms_elems * sizeof(float);
    const size_t cp_off  = xp_off + (size_t)NROWS * DIM * sizeof(unsigned short);
    const size_t ws_need = cp_off + (size_t)NCENT * DIM * sizeof(unsigned short);

    hipMemsetAsync(d_out, 0, (size_t)out_size * sizeof(float), stream);
    float* norms = (float*)d_ws;
    norms_kernel<<<(NROWS + NCENT) / 4, 256, 0, stream>>>(x, cent, norms);

    if (ws_size >= ws_need) {
        unsigned short* xp = (unsigned short*)((char*)d_ws + xp_off);
        unsigned short* cp = (unsigned short*)((char*)d_ws + cp_off);
        pack_kernel<<<((NROWS + NCENT) / 16 * 8) / 4, 256, 0, stream>>>(x, cent, xp, cp);
        rbf_stream<<<2048, 64, 0, stream>>>(xp, cp, w, sig, norms, out);
    } else {
        rbf_kernel<<<dim3(NCENT / 64, NROWS / 64), 256, 0, stream>>>(x, cent, w, sig, norms, out);
    }
}